// Round 5
// baseline (467.309 us; speedup 1.0000x reference)
//
#include <hip/hip_runtime.h>

#define HH 2048
#define WW 2048
constexpr float DT = 0.01f;
constexpr float VISC = 0.001f;

// ---------------------------------------------------------------- bilerp ----
__device__ __forceinline__ float bilerp(const float* __restrict__ f, int h, int w,
                                        float y, float x) {
    int x0 = (int)floorf(x);
    int y0 = (int)floorf(y);
    int x1 = x0 + 1, y1 = y0 + 1;
    x0 = min(max(x0, 0), w - 1);
    x1 = min(max(x1, 0), w - 1);
    y0 = min(max(y0, 0), h - 1);
    y1 = min(max(y1, 0), h - 1);
    float x0f = (float)x0, x1f = (float)x1, y0f = (float)y0, y1f = (float)y1;
    float wa = (x1f - x) * (y1f - y);
    float wb = (x - x0f) * (y1f - y);
    float wc = (x1f - x) * (y - y0f);
    float wd = (x - x0f) * (y - y0f);
    return wa * f[y0 * w + x0] + wb * f[y0 * w + x1] +
           wc * f[y1 * w + x0] + wd * f[y1 * w + x1];
}

// --------------------------------------------------------------- diffuse ----
__global__ void k_diffuse_u(const float* __restrict__ u, float* __restrict__ out) {
    int j = blockIdx.x * blockDim.x + threadIdx.x;
    int i = blockIdx.y;
    const int h = HH + 1, w = WW;
    if (j >= w) return;
    int jm = max(j - 1, 0), jp = min(j + 1, w - 1);
    int im = max(i - 1, 0), ip = min(i + 1, h - 1);
    float c = u[(size_t)i * w + j];
    float lap = u[(size_t)im * w + j] + u[(size_t)ip * w + j] +
                u[(size_t)i * w + jm] + u[(size_t)i * w + jp] - 4.0f * c;
    out[(size_t)i * w + j] = c + (DT * VISC) * lap;
}

__device__ __forceinline__ float v_forced(const float* __restrict__ v,
                                          const float* __restrict__ den,
                                          int i, int j) {
    float val = v[(size_t)i * (WW + 1) + j];
    if (j < WW) val += DT * (den[(size_t)i * WW + j] * 0.1f);
    return val;
}

__global__ void k_diffuse_v(const float* __restrict__ v, const float* __restrict__ den,
                            float* __restrict__ out) {
    int j = blockIdx.x * blockDim.x + threadIdx.x;
    int i = blockIdx.y;
    const int h = HH, w = WW + 1;
    if (j >= w) return;
    int jm = max(j - 1, 0), jp = min(j + 1, w - 1);
    int im = max(i - 1, 0), ip = min(i + 1, h - 1);
    float c = v_forced(v, den, i, j);
    float lap = v_forced(v, den, im, j) + v_forced(v, den, ip, j) +
                v_forced(v, den, i, jm) + v_forced(v, den, i, jp) - 4.0f * c;
    out[(size_t)i * w + j] = c + (DT * VISC) * lap;
}

__global__ void k_diffuse_d(const float* __restrict__ d, float* __restrict__ out) {
    int j = blockIdx.x * blockDim.x + threadIdx.x;
    int i = blockIdx.y;
    const int h = HH, w = WW;
    if (j >= w) return;
    int jm = max(j - 1, 0), jp = min(j + 1, w - 1);
    int im = max(i - 1, 0), ip = min(i + 1, h - 1);
    float c = d[(size_t)i * w + j];
    float lap = d[(size_t)im * w + j] + d[(size_t)ip * w + j] +
                d[(size_t)i * w + jm] + d[(size_t)i * w + jp] - 4.0f * c;
    out[(size_t)i * w + j] = c + (DT * (VISC * 0.1f)) * lap;
}

// ------------------------------------------------------------ divergence ----
__global__ void k_div(const float* __restrict__ u, const float* __restrict__ v,
                      float* __restrict__ dv) {
    int j = blockIdx.x * blockDim.x + threadIdx.x;
    int i = blockIdx.y;
    if (j >= WW) return;
    float val = (u[(size_t)(i + 1) * WW + j] - u[(size_t)i * WW + j] +
                 v[(size_t)i * (WW + 1) + j + 1] - v[(size_t)i * (WW + 1) + j]) / DT;
    dv[(size_t)i * WW + j] = val;
}

// ---------------------------------------------------- fused Jacobi (K=4) ----
// LDS halo scheme: tile 64x64 output, halo K. After iteration t, LDS rings
// >= t hold globally-correct values; output (rings >= K) is exact after K
// iterations. Contaminated rings < K are never read by correct-region cells.
// p is implicitly 0 on the domain boundary and outside; the inner-domain
// mask reproduces that each iteration. first=1 starts from p=0 (equivalent
// to the reference's first iteration from the zero p input).
#define TILE 64
#define KF 4
#define LW (TILE + 2 * KF)   // 72

__global__ __launch_bounds__(256) void k_jacobi_fused(
    const float* __restrict__ pin_g, const float* __restrict__ div_g,
    float* __restrict__ pout_g, int first) {
    __shared__ float pA[LW * LW];
    __shared__ float pB[LW * LW];
    __shared__ float dh[LW * LW];

    const int t = threadIdx.x;
    const int gx0 = blockIdx.x * TILE - KF;
    const int gy0 = blockIdx.y * TILE - KF;

    for (int idx = t; idx < LW * LW; idx += 256) {
        int y = idx / LW, x = idx - y * LW;
        int gy = gy0 + y, gx = gx0 + x;
        bool in = (gy >= 0) && (gy < HH) && (gx >= 0) && (gx < WW);
        size_t g = (size_t)gy * WW + gx;
        dh[idx] = in ? div_g[g] : 0.0f;
        pA[idx] = (first || !in) ? 0.0f : pin_g[g];
        pB[idx] = 0.0f;
    }
    __syncthreads();

    float* pa = pA;
    float* pb = pB;
    for (int it = 0; it < KF; ++it) {
        for (int idx = t; idx < (LW - 2) * (LW - 2); idx += 256) {
            int y = 1 + idx / (LW - 2);
            int x = 1 + idx % (LW - 2);
            int gy = gy0 + y, gx = gx0 + x;
            float val = 0.0f;
            if ((gy > 0) && (gy < HH - 1) && (gx > 0) && (gx < WW - 1)) {
                val = 0.25f * (pa[(y - 1) * LW + x] + pa[(y + 1) * LW + x] +
                               pa[y * LW + x - 1] + pa[y * LW + x + 1] -
                               dh[y * LW + x]);
            }
            pb[y * LW + x] = val;
        }
        __syncthreads();
        float* tmp = pa; pa = pb; pb = tmp;
    }

    for (int idx = t; idx < TILE * TILE; idx += 256) {
        int y = KF + idx / TILE;
        int x = KF + idx % TILE;
        int gy = gy0 + y, gx = gx0 + x;
        pout_g[(size_t)gy * WW + gx] = pa[y * LW + x];
    }
}

// --------------------------------------------------------------- project ----
__global__ void k_project_u(float* __restrict__ u, const float* __restrict__ p) {
    int j = blockIdx.x * blockDim.x + threadIdx.x;
    int i = blockIdx.y + 1;
    if (j >= WW) return;
    u[(size_t)i * WW + j] -= DT * (p[(size_t)i * WW + j] - p[(size_t)(i - 1) * WW + j]);
}

__global__ void k_project_v(float* __restrict__ v, const float* __restrict__ p) {
    int j = blockIdx.x * blockDim.x + threadIdx.x + 1;
    int i = blockIdx.y;
    if (j > WW - 1) return;
    v[(size_t)i * (WW + 1) + j] -= DT * (p[(size_t)i * WW + j] - p[(size_t)i * WW + j - 1]);
}

// ---------------------------------------------------------------- advect ----
__global__ void k_advect_u(const float* __restrict__ uf, const float* __restrict__ vf,
                           float* __restrict__ out) {
    int j = blockIdx.x * blockDim.x + threadIdx.x;
    int i = blockIdx.y;
    const int h = HH + 1, w = WW;
    if (j >= w) return;
    float X = (float)j, Y = (float)i;
    float x_u = fminf(fmaxf(X + 0.5f, 0.0f), (float)(WW - 1));
    float u_i = bilerp(uf, HH + 1, WW, Y, x_u);
    float y_v = fminf(fmaxf(Y + 0.5f, 0.0f), (float)(HH - 1));
    float v_i = bilerp(vf, HH, WW + 1, y_v, X);
    float px = fminf(fmaxf(X - DT * u_i, 0.0f), (float)(w - 1));
    float py = fminf(fmaxf(Y - DT * v_i, 0.0f), (float)(h - 1));
    out[(size_t)i * w + j] = bilerp(uf, h, w, py, px);
}

__global__ void k_advect_v(const float* __restrict__ vf, const float* __restrict__ un,
                           float* __restrict__ out) {
    int j = blockIdx.x * blockDim.x + threadIdx.x;
    int i = blockIdx.y;
    const int h = HH, w = WW + 1;
    if (j >= w) return;
    float X = (float)j, Y = (float)i;
    float x_u = fminf(fmaxf(X + 0.5f, 0.0f), (float)(WW - 1));
    float u_i = bilerp(un, HH + 1, WW, Y, x_u);
    float y_v = fminf(fmaxf(Y + 0.5f, 0.0f), (float)(HH - 1));
    float v_i = bilerp(vf, HH, WW + 1, y_v, X);
    float px = fminf(fmaxf(X - DT * u_i, 0.0f), (float)(w - 1));
    float py = fminf(fmaxf(Y - DT * v_i, 0.0f), (float)(h - 1));
    out[(size_t)i * w + j] = bilerp(vf, h, w, py, px);
}

__global__ void k_advect_d(const float* __restrict__ df, const float* __restrict__ un,
                           const float* __restrict__ vn, float* __restrict__ out) {
    int j = blockIdx.x * blockDim.x + threadIdx.x;
    int i = blockIdx.y;
    const int h = HH, w = WW;
    if (j >= w) return;
    float X = (float)j, Y = (float)i;
    float x_u = fminf(fmaxf(X + 0.5f, 0.0f), (float)(WW - 1));
    float u_i = bilerp(un, HH + 1, WW, Y, x_u);
    float y_v = fminf(fmaxf(Y + 0.5f, 0.0f), (float)(HH - 1));
    float v_i = bilerp(vn, HH, WW + 1, y_v, X);
    float px = fminf(fmaxf(X - DT * u_i, 0.0f), (float)(w - 1));
    float py = fminf(fmaxf(Y - DT * v_i, 0.0f), (float)(h - 1));
    out[(size_t)i * w + j] = 0.995f * bilerp(df, h, w, py, px);
}

// ---------------------------------------------------------------- launch ----
extern "C" void kernel_launch(void* const* d_in, const int* in_sizes, int n_in,
                              void* d_out, int out_size, void* d_ws, size_t ws_size,
                              hipStream_t stream) {
    const float* u_in   = (const float*)d_in[0];
    const float* v_in   = (const float*)d_in[1];
    const float* den_in = (const float*)d_in[2];
    float* out = (float*)d_out;

    const size_t SZ_UV = (size_t)(HH + 1) * WW;
    const size_t SZ_D  = (size_t)HH * WW;

    float* ws = (float*)d_ws;
    float* uA = ws;  ws += SZ_UV;
    float* uB = ws;  ws += SZ_UV;
    float* vA = ws;  ws += SZ_UV;
    float* vB = ws;  ws += SZ_UV;
    float* dA = ws;  ws += SZ_D;
    float* dv = ws;  ws += SZ_D;
    float* p0 = ws;  ws += SZ_D;
    float* p1 = ws;  ws += SZ_D;

    dim3 blk(256, 1, 1);
    dim3 gU((WW + 255) / 256, HH + 1);
    dim3 gV((WW + 1 + 255) / 256, HH);
    dim3 gD((WW + 255) / 256, HH);

    k_diffuse_u<<<gU, blk, 0, stream>>>(u_in, uA);
    k_diffuse_v<<<gV, blk, 0, stream>>>(v_in, den_in, vA);
    k_diffuse_d<<<gD, blk, 0, stream>>>(den_in, dA);

    k_div<<<gD, blk, 0, stream>>>(uA, vA, dv);

    // 20 Jacobi iterations = 5 launches x 4 fused (first starts from p=0).
    dim3 gJ(WW / TILE, HH / TILE);  // 32 x 32
    k_jacobi_fused<<<gJ, blk, 0, stream>>>(dv /*unused*/, dv, p1, 1);
    float* pin = p1;
    float* pout = p0;
    for (int l = 1; l < 5; ++l) {
        k_jacobi_fused<<<gJ, blk, 0, stream>>>(pin, dv, pout, 0);
        float* t = pin; pin = pout; pout = t;
    }
    // final pressure in `pin`

    dim3 gPU((WW + 255) / 256, HH - 1);
    k_project_u<<<gPU, blk, 0, stream>>>(uA, pin);
    dim3 gPV((WW - 1 + 255) / 256, HH);
    k_project_v<<<gPV, blk, 0, stream>>>(vA, pin);

    k_advect_u<<<gU, blk, 0, stream>>>(uA, vA, uB);
    k_advect_v<<<gV, blk, 0, stream>>>(vA, uB, vB);
    k_advect_d<<<gD, blk, 0, stream>>>(dA, uB, vB, out);
}

// Round 6
// 317.286 us; speedup vs baseline: 1.4728x; 1.4728x over previous
//
#include <hip/hip_runtime.h>

#define HH 2048
#define WW 2048
constexpr float DT = 0.01f;
constexpr float VISC = 0.001f;

// ---------------------------------------------------------------- bilerp ----
__device__ __forceinline__ float bilerp(const float* __restrict__ f, int h, int w,
                                        float y, float x) {
    int x0 = (int)floorf(x);
    int y0 = (int)floorf(y);
    int x1 = x0 + 1, y1 = y0 + 1;
    x0 = min(max(x0, 0), w - 1);
    x1 = min(max(x1, 0), w - 1);
    y0 = min(max(y0, 0), h - 1);
    y1 = min(max(y1, 0), h - 1);
    float x0f = (float)x0, x1f = (float)x1, y0f = (float)y0, y1f = (float)y1;
    float wa = (x1f - x) * (y1f - y);
    float wb = (x - x0f) * (y1f - y);
    float wc = (x1f - x) * (y - y0f);
    float wd = (x - x0f) * (y - y0f);
    return wa * f[y0 * w + x0] + wb * f[y0 * w + x1] +
           wc * f[y1 * w + x0] + wd * f[y1 * w + x1];
}

// --------------------------------------------------------------- diffuse ----
__global__ void k_diffuse_u(const float* __restrict__ u, float* __restrict__ out) {
    int j = blockIdx.x * blockDim.x + threadIdx.x;
    int i = blockIdx.y;
    const int h = HH + 1, w = WW;
    if (j >= w) return;
    int jm = max(j - 1, 0), jp = min(j + 1, w - 1);
    int im = max(i - 1, 0), ip = min(i + 1, h - 1);
    float c = u[(size_t)i * w + j];
    float lap = u[(size_t)im * w + j] + u[(size_t)ip * w + j] +
                u[(size_t)i * w + jm] + u[(size_t)i * w + jp] - 4.0f * c;
    out[(size_t)i * w + j] = c + (DT * VISC) * lap;
}

__device__ __forceinline__ float v_forced(const float* __restrict__ v,
                                          const float* __restrict__ den,
                                          int i, int j) {
    float val = v[(size_t)i * (WW + 1) + j];
    if (j < WW) val += DT * (den[(size_t)i * WW + j] * 0.1f);
    return val;
}

__global__ void k_diffuse_v(const float* __restrict__ v, const float* __restrict__ den,
                            float* __restrict__ out) {
    int j = blockIdx.x * blockDim.x + threadIdx.x;
    int i = blockIdx.y;
    const int h = HH, w = WW + 1;
    if (j >= w) return;
    int jm = max(j - 1, 0), jp = min(j + 1, w - 1);
    int im = max(i - 1, 0), ip = min(i + 1, h - 1);
    float c = v_forced(v, den, i, j);
    float lap = v_forced(v, den, im, j) + v_forced(v, den, ip, j) +
                v_forced(v, den, i, jm) + v_forced(v, den, i, jp) - 4.0f * c;
    out[(size_t)i * w + j] = c + (DT * VISC) * lap;
}

__global__ void k_diffuse_d(const float* __restrict__ d, float* __restrict__ out) {
    int j = blockIdx.x * blockDim.x + threadIdx.x;
    int i = blockIdx.y;
    const int h = HH, w = WW;
    if (j >= w) return;
    int jm = max(j - 1, 0), jp = min(j + 1, w - 1);
    int im = max(i - 1, 0), ip = min(i + 1, h - 1);
    float c = d[(size_t)i * w + j];
    float lap = d[(size_t)im * w + j] + d[(size_t)ip * w + j] +
                d[(size_t)i * w + jm] + d[(size_t)i * w + jp] - 4.0f * c;
    out[(size_t)i * w + j] = c + (DT * (VISC * 0.1f)) * lap;
}

// ------------------------------------------------------------ divergence ----
__global__ void k_div(const float* __restrict__ u, const float* __restrict__ v,
                      float* __restrict__ dv) {
    int j = blockIdx.x * blockDim.x + threadIdx.x;
    int i = blockIdx.y;
    if (j >= WW) return;
    float val = (u[(size_t)(i + 1) * WW + j] - u[(size_t)i * WW + j] +
                 v[(size_t)i * (WW + 1) + j + 1] - v[(size_t)i * (WW + 1) + j]) / DT;
    dv[(size_t)i * WW + j] = val;
}

// ---------------------------------------------------- fused Jacobi (K=4) ----
// TILE=56 output, halo 4 -> LDS rows of LW=64 (power-of-2 indexing, no
// div/mod). div held in registers (16/thread). All LDS stencil traffic via
// float4 (ds_read_b128). Ring >= t is exact after iteration t; the stored
// central 56x56 (ring >= 4) is exact after 4 iterations. Contaminated rings
// hold finite junk that the exact region never reads. Boundary cells
// (global ring 0) are recomputed as 0 each iteration, matching the
// reference's zeros.at[inner].set(...). FP order: (((up+dn)+l)+r)-div.
#define TILE 56
#define KF 4
#define LW 64

__global__ __launch_bounds__(256) void k_jacobi_fused(
    const float* __restrict__ pin_g, const float* __restrict__ div_g,
    float* __restrict__ pout_g, int first) {
    __shared__ float pA[LW * LW];
    __shared__ float pB[LW * LW];

    const int t = threadIdx.x;
    const int gx0 = blockIdx.x * TILE - KF;
    const int gy0 = blockIdx.y * TILE - KF;

    float dreg[16];

    // zero pB (rows 0/63 must be zero; the rest is overwritten every iter)
    #pragma unroll
    for (int c = 0; c < 4; ++c)
        reinterpret_cast<float4*>(pB)[c * 256 + t] = make_float4(0.f, 0.f, 0.f, 0.f);

    // ---- load: pin -> pA, div -> registers (chunk ci: y=ci>>4, x=(ci&15)*4)
    #pragma unroll
    for (int c = 0; c < 4; ++c) {
        const int ci = c * 256 + t;
        const int y = ci >> 4;
        const int x = (ci & 15) * 4;
        const int gy = gy0 + y;
        const int gxb = gx0 + x;
        float4 pv = make_float4(0.f, 0.f, 0.f, 0.f);
        float4 dv4 = make_float4(0.f, 0.f, 0.f, 0.f);
        const bool rowin = (gy >= 0) && (gy < HH);
        if (rowin && gxb >= 0 && gxb + 3 < WW) {
            const size_t g = (size_t)gy * WW + gxb;
            dv4 = *reinterpret_cast<const float4*>(div_g + g);
            if (!first) pv = *reinterpret_cast<const float4*>(pin_g + g);
        } else if (rowin) {
            #pragma unroll
            for (int e = 0; e < 4; ++e) {
                const int gx = gxb + e;
                if (gx >= 0 && gx < WW) {
                    const size_t g = (size_t)gy * WW + gx;
                    (&dv4.x)[e] = div_g[g];
                    if (!first) (&pv.x)[e] = pin_g[g];
                }
            }
        }
        *reinterpret_cast<float4*>(&pA[y * LW + x]) = pv;
        dreg[c * 4 + 0] = dv4.x; dreg[c * 4 + 1] = dv4.y;
        dreg[c * 4 + 2] = dv4.z; dreg[c * 4 + 3] = dv4.w;
    }
    __syncthreads();

    float* pa = pA;
    float* pb = pB;
    for (int it = 0; it < KF; ++it) {
        #pragma unroll
        for (int c = 0; c < 4; ++c) {
            const int ci = c * 256 + t;
            const int y = ci >> 4;
            const int x = (ci & 15) * 4;
            if (y >= 1 && y <= LW - 2) {
                const float4 up = *reinterpret_cast<const float4*>(&pa[(y - 1) * LW + x]);
                const float4 dn = *reinterpret_cast<const float4*>(&pa[(y + 1) * LW + x]);
                const float4 ce = *reinterpret_cast<const float4*>(&pa[y * LW + x]);
                const float lf = (x > 0)      ? pa[y * LW + x - 1] : 0.f;
                const float rt = (x + 4 < LW) ? pa[y * LW + x + 4] : 0.f;
                const int gy = gy0 + y;
                const bool rowin = (gy > 0) && (gy < HH - 1);
                const int gxb = gx0 + x;
                float4 o;
                o.x = (rowin && gxb + 0 > 0 && gxb + 0 < WW - 1 && x + 0 > 0)
                      ? 0.25f * ((((up.x + dn.x) + lf) + ce.y) - dreg[c * 4 + 0]) : 0.f;
                o.y = (rowin && gxb + 1 > 0 && gxb + 1 < WW - 1)
                      ? 0.25f * ((((up.y + dn.y) + ce.x) + ce.z) - dreg[c * 4 + 1]) : 0.f;
                o.z = (rowin && gxb + 2 > 0 && gxb + 2 < WW - 1)
                      ? 0.25f * ((((up.z + dn.z) + ce.y) + ce.w) - dreg[c * 4 + 2]) : 0.f;
                o.w = (rowin && gxb + 3 > 0 && gxb + 3 < WW - 1 && x + 3 < LW - 1)
                      ? 0.25f * ((((up.w + dn.w) + ce.z) + rt) - dreg[c * 4 + 3]) : 0.f;
                *reinterpret_cast<float4*>(&pb[y * LW + x]) = o;
            }
        }
        __syncthreads();
        float* tmp = pa; pa = pb; pb = tmp;
    }
    // KF even -> result is back in pA (== pa)

    // ---- store central TILE x TILE (local [KF, KF+TILE))
    #pragma unroll
    for (int c = 0; c < 4; ++c) {
        const int ci = c * 256 + t;
        const int y = ci >> 4;
        const int x = (ci & 15) * 4;
        if (y >= KF && y < KF + TILE && x >= KF && x < KF + TILE) {
            const int gy = gy0 + y;
            const int gxb = gx0 + x;
            if (gy < HH) {
                if (gxb + 3 < WW) {
                    *reinterpret_cast<float4*>(pout_g + (size_t)gy * WW + gxb) =
                        *reinterpret_cast<const float4*>(&pa[y * LW + x]);
                } else {
                    #pragma unroll
                    for (int e = 0; e < 4; ++e) {
                        const int gx = gxb + e;
                        if (gx < WW) pout_g[(size_t)gy * WW + gx] = pa[y * LW + x + e];
                    }
                }
            }
        }
    }
}

// --------------------------------------------------------------- project ----
__global__ void k_project_u(float* __restrict__ u, const float* __restrict__ p) {
    int j = blockIdx.x * blockDim.x + threadIdx.x;
    int i = blockIdx.y + 1;
    if (j >= WW) return;
    u[(size_t)i * WW + j] -= DT * (p[(size_t)i * WW + j] - p[(size_t)(i - 1) * WW + j]);
}

__global__ void k_project_v(float* __restrict__ v, const float* __restrict__ p) {
    int j = blockIdx.x * blockDim.x + threadIdx.x + 1;
    int i = blockIdx.y;
    if (j > WW - 1) return;
    v[(size_t)i * (WW + 1) + j] -= DT * (p[(size_t)i * WW + j] - p[(size_t)i * WW + j - 1]);
}

// ---------------------------------------------------------------- advect ----
__global__ void k_advect_u(const float* __restrict__ uf, const float* __restrict__ vf,
                           float* __restrict__ out) {
    int j = blockIdx.x * blockDim.x + threadIdx.x;
    int i = blockIdx.y;
    const int h = HH + 1, w = WW;
    if (j >= w) return;
    float X = (float)j, Y = (float)i;
    float x_u = fminf(fmaxf(X + 0.5f, 0.0f), (float)(WW - 1));
    float u_i = bilerp(uf, HH + 1, WW, Y, x_u);
    float y_v = fminf(fmaxf(Y + 0.5f, 0.0f), (float)(HH - 1));
    float v_i = bilerp(vf, HH, WW + 1, y_v, X);
    float px = fminf(fmaxf(X - DT * u_i, 0.0f), (float)(w - 1));
    float py = fminf(fmaxf(Y - DT * v_i, 0.0f), (float)(h - 1));
    out[(size_t)i * w + j] = bilerp(uf, h, w, py, px);
}

__global__ void k_advect_v(const float* __restrict__ vf, const float* __restrict__ un,
                           float* __restrict__ out) {
    int j = blockIdx.x * blockDim.x + threadIdx.x;
    int i = blockIdx.y;
    const int h = HH, w = WW + 1;
    if (j >= w) return;
    float X = (float)j, Y = (float)i;
    float x_u = fminf(fmaxf(X + 0.5f, 0.0f), (float)(WW - 1));
    float u_i = bilerp(un, HH + 1, WW, Y, x_u);
    float y_v = fminf(fmaxf(Y + 0.5f, 0.0f), (float)(HH - 1));
    float v_i = bilerp(vf, HH, WW + 1, y_v, X);
    float px = fminf(fmaxf(X - DT * u_i, 0.0f), (float)(w - 1));
    float py = fminf(fmaxf(Y - DT * v_i, 0.0f), (float)(h - 1));
    out[(size_t)i * w + j] = bilerp(vf, h, w, py, px);
}

__global__ void k_advect_d(const float* __restrict__ df, const float* __restrict__ un,
                           const float* __restrict__ vn, float* __restrict__ out) {
    int j = blockIdx.x * blockDim.x + threadIdx.x;
    int i = blockIdx.y;
    const int h = HH, w = WW;
    if (j >= w) return;
    float X = (float)j, Y = (float)i;
    float x_u = fminf(fmaxf(X + 0.5f, 0.0f), (float)(WW - 1));
    float u_i = bilerp(un, HH + 1, WW, Y, x_u);
    float y_v = fminf(fmaxf(Y + 0.5f, 0.0f), (float)(HH - 1));
    float v_i = bilerp(vn, HH, WW + 1, y_v, X);
    float px = fminf(fmaxf(X - DT * u_i, 0.0f), (float)(w - 1));
    float py = fminf(fmaxf(Y - DT * v_i, 0.0f), (float)(h - 1));
    out[(size_t)i * w + j] = 0.995f * bilerp(df, h, w, py, px);
}

// ---------------------------------------------------------------- launch ----
extern "C" void kernel_launch(void* const* d_in, const int* in_sizes, int n_in,
                              void* d_out, int out_size, void* d_ws, size_t ws_size,
                              hipStream_t stream) {
    const float* u_in   = (const float*)d_in[0];
    const float* v_in   = (const float*)d_in[1];
    const float* den_in = (const float*)d_in[2];
    float* out = (float*)d_out;

    const size_t SZ_UV = (size_t)(HH + 1) * WW;
    const size_t SZ_D  = (size_t)HH * WW;

    float* ws = (float*)d_ws;
    float* uA = ws;  ws += SZ_UV;
    float* uB = ws;  ws += SZ_UV;
    float* vA = ws;  ws += SZ_UV;
    float* vB = ws;  ws += SZ_UV;
    float* dA = ws;  ws += SZ_D;
    float* dv = ws;  ws += SZ_D;
    float* p0 = ws;  ws += SZ_D;
    float* p1 = ws;  ws += SZ_D;

    dim3 blk(256, 1, 1);
    dim3 gU((WW + 255) / 256, HH + 1);
    dim3 gV((WW + 1 + 255) / 256, HH);
    dim3 gD((WW + 255) / 256, HH);

    k_diffuse_u<<<gU, blk, 0, stream>>>(u_in, uA);
    k_diffuse_v<<<gV, blk, 0, stream>>>(v_in, den_in, vA);
    k_diffuse_d<<<gD, blk, 0, stream>>>(den_in, dA);

    k_div<<<gD, blk, 0, stream>>>(uA, vA, dv);

    // 20 Jacobi iterations = 5 launches x 4 fused (first starts from p=0).
    dim3 gJ((WW + TILE - 1) / TILE, (HH + TILE - 1) / TILE);  // 37 x 37
    k_jacobi_fused<<<gJ, blk, 0, stream>>>(dv /*unused*/, dv, p1, 1);
    float* pin = p1;
    float* pout = p0;
    for (int l = 1; l < 5; ++l) {
        k_jacobi_fused<<<gJ, blk, 0, stream>>>(pin, dv, pout, 0);
        float* t = pin; pin = pout; pout = t;
    }
    // final pressure in `pin`

    dim3 gPU((WW + 255) / 256, HH - 1);
    k_project_u<<<gPU, blk, 0, stream>>>(uA, pin);
    dim3 gPV((WW - 1 + 255) / 256, HH);
    k_project_v<<<gPV, blk, 0, stream>>>(vA, pin);

    k_advect_u<<<gU, blk, 0, stream>>>(uA, vA, uB);
    k_advect_v<<<gV, blk, 0, stream>>>(vA, uB, vB);
    k_advect_d<<<gD, blk, 0, stream>>>(dA, uB, vB, out);
}